// Round 5
// baseline (30.699 us; speedup 1.0000x reference)
//
#include <hip/hip_runtime.h>

#define IMG   480
#define OUT   224
#define BATCH 128
#define CHAN  3
#define YT    16            // output rows per block tile
#define NTILE (OUT / YT)    // 14 tiles per (b,c) plane

// One block = 4 waves; wave w owns output columns [64w, 64w+64) (last wave: 32 cols).
// Each wave streams source rows through a 2-row register window:
//   h_cur = horizontal lerp of source row 'cur' at this lane's x  (1 lerp per src row)
//   output row y = h(y0)*(1-wy) + h(y1)*wy                         (1 lerp + 1 store)
// No LDS, no barriers, wave-uniform control flow.
__global__ __launch_bounds__(256) void crop_resize_kernel(
    const float* __restrict__ img,   // [B, 3, 480, 480]
    const float* __restrict__ box,   // [B, 4] normalized cxcywh
    float* __restrict__ out)         // [B, 3*224*224]
{
    const int bid = blockIdx.x;
    const int yt  = bid % NTILE;
    const int bc  = bid / NTILE;         // b*3 + c
    const int b   = bc / CHAN;

    const int x = threadIdx.x;           // output column owned by this thread
    if (x >= OUT) return;                // wave 3: upper 32 lanes idle

    // ---- box math (matches reference exactly: *480, cxcywh->xyxy, trunc) ----
    const float fcx = box[b * 4 + 0] * (float)IMG;
    const float fcy = box[b * 4 + 1] * (float)IMG;
    const float fw  = box[b * 4 + 2] * (float)IMG;
    const float fh  = box[b * 4 + 3] * (float)IMG;
    const int xa = (int)truncf(fcx - 0.5f * fw);
    const int ya = (int)truncf(fcy - 0.5f * fh);
    const int xb = (int)truncf(fcx + 0.5f * fw);
    const int yb = (int)truncf(fcy + 0.5f * fh);
    const int icw = xb - xa, ich = yb - ya;       // crop extent, 96..240
    const float cw = (float)icw, ch = (float)ich;

    const float sch = ch * (1.0f / (float)OUT);
    const float scw = cw * (1.0f / (float)OUT);

    // ---- per-lane x geometry (computed once) ----
    float sx = fminf(fmaxf(((float)x + 0.5f) * scw - 0.5f, 0.0f), cw - 1.0f);
    const int   x0   = (int)floorf(sx);
    const float wx   = sx - (float)x0;
    const float omwx = 1.0f - wx;
    const int   x1   = min(x0 + 1, icw - 1);

    const float* __restrict__ crop0 =
        img + (size_t)bc * (IMG * IMG) + (size_t)ya * IMG + xa;  // crop row r: crop0 + r*IMG

    const int ybase = yt * YT;

    // rolling 2-row window of horizontally-resampled source rows
    float h_prev = 0.0f, h_cur = 0.0f;
    int cur;   // index of source row currently in h_cur
    {
        float syf = fminf(fmaxf(((float)ybase + 0.5f) * sch - 0.5f, 0.0f), ch - 1.0f);
        cur = (int)floorf(syf) - 1;      // so the first while-advance loads y0 first
    }

    float* __restrict__ orow = out + ((size_t)bc * OUT + ybase) * OUT + x;

    for (int yy = 0; yy < YT; ++yy) {
        const int y = ybase + yy;
        float sy = fminf(fmaxf(((float)y + 0.5f) * sch - 0.5f, 0.0f), ch - 1.0f);
        const int   y0 = (int)floorf(sy);
        const float wy = sy - (float)y0;
        const int   y1 = min(y0 + 1, ich - 1);

        // advance window until h_cur = row y1 (wave-uniform trip count: 0..2)
        while (cur < y1) {
            ++cur;
            h_prev = h_cur;
            const float* __restrict__ r = crop0 + (size_t)cur * IMG;
            h_cur = r[x0] * omwx + r[x1] * wx;
        }
        // top row: y0 == cur only in the bottom-clamp case (y1 == y0)
        const float top = (y0 == cur) ? h_cur : h_prev;
        orow[(size_t)yy * OUT] = top * (1.0f - wy) + h_cur * wy;
    }
}

extern "C" void kernel_launch(void* const* d_in, const int* in_sizes, int n_in,
                              void* d_out, int out_size, void* d_ws, size_t ws_size,
                              hipStream_t stream) {
    const float* img = (const float*)d_in[0];
    const float* box = (const float*)d_in[1];
    float* out = (float*)d_out;

    const int grid = BATCH * CHAN * NTILE;   // 5376 blocks
    crop_resize_kernel<<<grid, 256, 0, stream>>>(img, box, out);
}

// Round 6
// 26.025 us; speedup vs baseline: 1.1796x; 1.1796x over previous
//
#include <hip/hip_runtime.h>

#define IMG   480
#define OUT   224
#define BATCH 128
#define CHAN  3
#define YT    16            // output rows per block tile
#define NTILE (OUT / YT)    // 14 tiles per (b,c) plane
#define NCOL  248           // intermediate row stride (floats); max used 244

__global__ __launch_bounds__(256) void crop_resize_kernel(
    const float* __restrict__ img,   // [B, 3, 480, 480]
    const float* __restrict__ box,   // [B, 4] normalized cxcywh
    float* __restrict__ out)         // [B, 3*224*224]
{
    __shared__ float inter[YT * NCOL];   // 15.5 KB: vertically-resized rows

    const int bid = blockIdx.x;
    const int yt  = bid % NTILE;
    const int bc  = bid / NTILE;         // b*3 + c
    const int b   = bc / CHAN;

    // ---- block-uniform box math (matches reference exactly) ----
    const float fcx = box[b * 4 + 0] * (float)IMG;
    const float fcy = box[b * 4 + 1] * (float)IMG;
    const float fw  = box[b * 4 + 2] * (float)IMG;
    const float fh  = box[b * 4 + 3] * (float)IMG;
    const int xa = (int)truncf(fcx - 0.5f * fw);
    const int ya = (int)truncf(fcy - 0.5f * fh);
    const int xb = (int)truncf(fcx + 0.5f * fw);
    const int yb = (int)truncf(fcy + 0.5f * fh);
    const int icw = xb - xa, ich = yb - ya;        // 96..240
    const float cw = (float)icw, ch = (float)ich;

    const float sch = ch * (1.0f / (float)OUT);
    const float scw = cw * (1.0f / (float)OUT);

    const int ybase = yt * YT;

    // ---- source col window, float4-aligned, +1 word for unconditional x0+1 tap ----
    const int cb   = xa & ~3;                    // aligned global col base
    const int dx   = xa - cb;                    // 0..3
    const int nw4e = (dx + icw + 1 + 3) >> 2;    // float4s per row, <= 61
    // global overread safety: cb + 4*nw4e <= xa + icw + 8 <= 440 < 480

    const float* __restrict__ plane = img + (size_t)bc * (IMG * IMG);

    // ---- pass 1: vertical lerp, global -> LDS (coalesced float4) ----
    const int lane = threadIdx.x & 63;
    const int wv   = threadIdx.x >> 6;
    #pragma unroll
    for (int k = 0; k < YT / 4; ++k) {           // 4 rows per wave
        const int yy = wv * (YT / 4) + k;
        const int y  = ybase + yy;
        float sy = fminf(fmaxf(((float)y + 0.5f) * sch - 0.5f, 0.0f), ch - 1.0f);
        const int   y0 = (int)floorf(sy);
        const float wy = sy - (float)y0;
        const int   y1 = min(y0 + 1, ich - 1);

        const float4* __restrict__ r0 =
            reinterpret_cast<const float4*>(plane + (size_t)(ya + y0) * IMG + cb);
        const float4* __restrict__ r1 =
            reinterpret_cast<const float4*>(plane + (size_t)(ya + y1) * IMG + cb);
        float4* drow = reinterpret_cast<float4*>(&inter[yy * NCOL]);

        if (lane < nw4e) {
            const float4 a = r0[lane];
            const float4 c = r1[lane];
            float4 v;
            v.x = a.x * (1.0f - wy) + c.x * wy;
            v.y = a.y * (1.0f - wy) + c.y * wy;
            v.z = a.z * (1.0f - wy) + c.z * wy;
            v.w = a.w * (1.0f - wy) + c.w * wy;
            drow[lane] = v;
        }
    }
    __syncthreads();

    // ---- pass 2: horizontal lerp, LDS -> out; fixed column per thread ----
    const int x = threadIdx.x;                   // output column; 224 of 256 active
    if (x < OUT) {
        float sx = fminf(fmaxf(((float)x + 0.5f) * scw - 0.5f, 0.0f), cw - 1.0f);
        const int   x0   = (int)floorf(sx);
        const float wx   = sx - (float)x0;       // wx==0 whenever x0==icw-1 (edge clamp)
        const float omwx = 1.0f - wx;

        const float* __restrict__ rbase = &inter[dx + x0];
        float* __restrict__ op = out + ((size_t)bc * OUT + ybase) * OUT + x;

        #pragma unroll
        for (int yy = 0; yy < YT; ++yy) {
            const float a = rbase[yy * NCOL];        // same base, adjacent dwords:
            const float c = rbase[yy * NCOL + 1];    // merges to ds_read2_b32
            op[(size_t)yy * OUT] = a * omwx + c * wx;
        }
    }
}

extern "C" void kernel_launch(void* const* d_in, const int* in_sizes, int n_in,
                              void* d_out, int out_size, void* d_ws, size_t ws_size,
                              hipStream_t stream) {
    const float* img = (const float*)d_in[0];
    const float* box = (const float*)d_in[1];
    float* out = (float*)d_out;

    const int grid = BATCH * CHAN * NTILE;   // 5376 blocks
    crop_resize_kernel<<<grid, 256, 0, stream>>>(img, box, out);
}

// Round 7
// 25.851 us; speedup vs baseline: 1.1875x; 1.0067x over previous
//
#include <hip/hip_runtime.h>

#define IMG   480
#define OUT   224
#define BATCH 128
#define CHAN  3
#define YT    16            // output rows per block tile
#define NTILE (OUT / YT)    // 14 tiles per (b,c) plane
#define NCOL  248           // intermediate row stride (floats); max used 244

__global__ __launch_bounds__(256) void crop_resize_kernel(
    const float* __restrict__ img,   // [B, 3, 480, 480]
    const float* __restrict__ box,   // [B, 4] normalized cxcywh
    float* __restrict__ out)         // [B, 3*224*224]
{
    __shared__ float inter[YT * NCOL];   // 15.5 KB: vertically-resized rows

    const int bid = blockIdx.x;
    const int yt  = bid % NTILE;
    const int bc  = bid / NTILE;         // b*3 + c
    const int b   = bc / CHAN;

    // ---- block-uniform box math (matches reference exactly) ----
    const float fcx = box[b * 4 + 0] * (float)IMG;
    const float fcy = box[b * 4 + 1] * (float)IMG;
    const float fw  = box[b * 4 + 2] * (float)IMG;
    const float fh  = box[b * 4 + 3] * (float)IMG;
    const int xa = (int)truncf(fcx - 0.5f * fw);
    const int ya = (int)truncf(fcy - 0.5f * fh);
    const int xb = (int)truncf(fcx + 0.5f * fw);
    const int yb = (int)truncf(fcy + 0.5f * fh);
    const int icw = xb - xa, ich = yb - ya;        // 96..240
    const float cw = (float)icw, ch = (float)ich;

    const float sch = ch * (1.0f / (float)OUT);
    const float scw = cw * (1.0f / (float)OUT);

    const int ybase = yt * YT;

    // ---- source col window, float4-aligned, +1 word for unconditional x0+1 tap ----
    const int cb   = xa & ~3;                    // aligned global col base
    const int dx   = xa - cb;                    // 0..3
    const int nw4e = (dx + icw + 1 + 3) >> 2;    // float4s per row, <= 61
    // global overread safety: cb + 4*nw4e <= xa + icw + 8 <= 440 < 480

    const float* __restrict__ plane = img + (size_t)bc * (IMG * IMG);

    // ---- pass 1: vertical lerp, global -> LDS (coalesced float4) ----
    const int lane = threadIdx.x & 63;
    const int wv   = threadIdx.x >> 6;
    #pragma unroll
    for (int k = 0; k < YT / 4; ++k) {           // 4 rows per wave
        const int yy = wv * (YT / 4) + k;
        const int y  = ybase + yy;
        float sy = fminf(fmaxf(((float)y + 0.5f) * sch - 0.5f, 0.0f), ch - 1.0f);
        const int   y0 = (int)floorf(sy);
        const float wy = sy - (float)y0;
        const int   y1 = min(y0 + 1, ich - 1);

        const float4* __restrict__ r0 =
            reinterpret_cast<const float4*>(plane + (size_t)(ya + y0) * IMG + cb);
        const float4* __restrict__ r1 =
            reinterpret_cast<const float4*>(plane + (size_t)(ya + y1) * IMG + cb);
        float4* drow = reinterpret_cast<float4*>(&inter[yy * NCOL]);

        if (lane < nw4e) {
            const float4 a = r0[lane];
            const float4 c = r1[lane];
            float4 v;
            v.x = a.x * (1.0f - wy) + c.x * wy;
            v.y = a.y * (1.0f - wy) + c.y * wy;
            v.z = a.z * (1.0f - wy) + c.z * wy;
            v.w = a.w * (1.0f - wy) + c.w * wy;
            drow[lane] = v;
        }
    }
    __syncthreads();

    // ---- pass 2: horizontal lerp, LDS -> out; fixed column per thread ----
    // nontemporal stores: out is write-once/never-read -> keep it out of L2
    // so cached source rows survive for the cross-row / cross-tile re-reads.
    const int x = threadIdx.x;                   // output column; 224 of 256 active
    if (x < OUT) {
        float sx = fminf(fmaxf(((float)x + 0.5f) * scw - 0.5f, 0.0f), cw - 1.0f);
        const int   x0   = (int)floorf(sx);
        const float wx   = sx - (float)x0;       // wx==0 whenever x0==icw-1 (edge clamp)
        const float omwx = 1.0f - wx;

        const float* __restrict__ rbase = &inter[dx + x0];
        float* __restrict__ op = out + ((size_t)bc * OUT + ybase) * OUT + x;

        #pragma unroll
        for (int yy = 0; yy < YT; ++yy) {
            const float a = rbase[yy * NCOL];        // same base, adjacent dwords:
            const float c = rbase[yy * NCOL + 1];    // merges to ds_read2_b32
            __builtin_nontemporal_store(a * omwx + c * wx, &op[(size_t)yy * OUT]);
        }
    }
}

extern "C" void kernel_launch(void* const* d_in, const int* in_sizes, int n_in,
                              void* d_out, int out_size, void* d_ws, size_t ws_size,
                              hipStream_t stream) {
    const float* img = (const float*)d_in[0];
    const float* box = (const float*)d_in[1];
    float* out = (float*)d_out;

    const int grid = BATCH * CHAN * NTILE;   // 5376 blocks
    crop_resize_kernel<<<grid, 256, 0, stream>>>(img, box, out);
}